// Round 9
// baseline (62.577 us; speedup 1.0000x reference)
//
#include <hip/hip_runtime.h>

#define P   7
#define GS  7
#define D   21
#define HH  80
#define WW  80
#define CC  (D * GS * GS)        // 1029
#define PLANE (HH * WW)          // 6400 floats
#define IW  81                   // integral-image stride (odd: conflict-free cumsums)
#define NSEG 5
#define SEGLEN 16

// fl32(1/7) = 0x3E124925 — the golden divides via reciprocal multiply.
__device__ __forceinline__ float recip7() {
    union { unsigned u; float f; } c; c.u = 0x3E124925u; return c.f;
}

// a*b + c with a HARD barrier between mul and add: no fma contraction ever.
__device__ __forceinline__ float mul_add_nofma(float a, float b, float c) {
    float t = a * b;
    asm volatile("" : "+v"(t));
    return t + c;
}

// ---------- compact: flat ordered per-batch list + base offsets -------------
__global__ __launch_bounds__(512) void compact_kernel(
    const float* __restrict__ rois, int R, int N,
    int* __restrict__ jlist, int* __restrict__ base)   // base[N+1]
{
    __shared__ int cntS[8];
    __shared__ int baseS[9];
    int wave = threadIdx.x >> 6, lane = threadIdx.x & 63;

    if (wave < N) {
        int b = wave, cnt = 0;
        for (int r0 = 0; r0 < R; r0 += 64) {
            int r = r0 + lane;
            bool m = (r < R) && ((int)rois[(size_t)r * 5] == b);
            cnt += __popcll(__ballot(m));
        }
        if (lane == 0) cntS[b] = cnt;
    }
    __syncthreads();
    if (threadIdx.x == 0) {
        int acc = 0;
        for (int b = 0; b < N; ++b) { baseS[b] = acc; acc += cntS[b]; }
        baseS[N] = acc;
    }
    __syncthreads();
    if (wave < N) {
        int b = wave, off = baseS[b];
        for (int r0 = 0; r0 < R; r0 += 64) {
            int r = r0 + lane;
            bool m = (r < R) && ((int)rois[(size_t)r * 5] == b);
            unsigned long long mask = __ballot(m);
            int pos = off + __popcll(mask & ((1ull << lane) - 1ull));
            if (m) jlist[pos] = r;
            off += __popcll(mask);
        }
    }
    if (threadIdx.x <= N) base[threadIdx.x] = baseS[threadIdx.x];
}

// ---------- edge table: tab2[rem*R + j], one thread per entry ---------------
__global__ __launch_bounds__(256) void edge_kernel(
    const float* __restrict__ rois, const int* __restrict__ jlist,
    const int* __restrict__ base, int N, int R,
    uint2* __restrict__ tab2)
{
    int t = blockIdx.x * 256 + threadIdx.x;
    if (t >= 49 * R) return;
    int rem = t / R;                 // 0..48
    int j   = t - rem * R;
    if (j >= base[N]) return;
    int gh = rem / 7, gw = rem % 7;
    int r = jlist[j];

    const float* roi = rois + (size_t)r * 5;
    float x1 = rintf(roi[1]) * 0.0625f;
    float y1 = rintf(roi[2]) * 0.0625f;
    float x2 = (rintf(roi[3]) + 1.0f) * 0.0625f;
    float y2 = (rintf(roi[4]) + 1.0f) * 0.0625f;
    float bin_w = fmaxf(x2 - x1, 0.1f) * recip7();
    float bin_h = fmaxf(y2 - y1, 0.1f) * recip7();
    asm volatile("" : "+v"(bin_w), "+v"(bin_h));

    float hs_f = floorf(mul_add_nofma((float)gh,       bin_h, y1));
    float he_f = ceilf (mul_add_nofma((float)(gh + 1), bin_h, y1));
    float ws_f = floorf(mul_add_nofma((float)gw,       bin_w, x1));
    float we_f = ceilf (mul_add_nofma((float)(gw + 1), bin_w, x1));
    int hs = (int)fminf(fmaxf(hs_f, 0.0f), 80.0f);
    int he = (int)fminf(fmaxf(he_f, 0.0f), 80.0f);
    int ws = (int)fminf(fmaxf(ws_f, 0.0f), 80.0f);
    int we = (int)fminf(fmaxf(we_f, 0.0f), 80.0f);

    int area = (he - hs) * (we - ws);
    float rcp = (area > 0) ? (1.0f / (float)area) : 0.0f;
    unsigned e = (unsigned)hs | ((unsigned)he << 8)
               | ((unsigned)ws << 16) | ((unsigned)we << 24);
    tab2[t] = make_uint2(e, __float_as_uint(rcp));
}

// ---------- plane kernel: LDS integral image + coalesced O(1) hot loop ------
__global__ __launch_bounds__(512) void psroi_plane_kernel(
    const float* __restrict__ feat, int R,
    const uint2* __restrict__ tab2,
    const int* __restrict__ jlist, const int* __restrict__ base,
    float* __restrict__ dst)          // ws_T[c][r]
{
    __shared__ float ii[IW * IW];     // 26.2 KB, zero border at row 0 / col 0
    __shared__ float tot[NSEG][HH];

    int tid = threadIdx.x;
    int bid = blockIdx.x;
    int b   = bid / CC;
    int c   = bid % CC;
    int rem = c % (GS * GS);          // gh*7+gw

    // ---- stage plane into ii[1..80][1..80], float4 global loads ----
    const float4* src4 = (const float4*)(feat + ((size_t)b * CC + c) * PLANE);
    for (int i = tid; i < PLANE / 4; i += 512) {
        float4 v = src4[i];
        int h = i / 20;
        int w = (i % 20) * 4;
        float* p = &ii[(h + 1) * IW + (w + 1)];
        p[0] = v.x; p[1] = v.y; p[2] = v.z; p[3] = v.w;
    }
    if (tid < IW) { ii[tid] = 0.0f; ii[tid * IW] = 0.0f; }
    __syncthreads();

    bool act = tid < NSEG * WW;
    int seg = tid / WW;                // 0..4
    int lw  = tid % WW;                // 0..79
    float v[SEGLEN];

    // ---- H cumsum (axis=2 first, as golden) ----
    {
        int col = lw + 1, h0 = seg * SEGLEN + 1;
        if (act) {
            float s = 0.0f;
            #pragma unroll
            for (int k = 0; k < SEGLEN; ++k) { v[k] = ii[(h0 + k) * IW + col]; s += v[k]; }
            tot[seg][lw] = s;
        }
        __syncthreads();
        if (act) {
            float off = 0.0f;
            #pragma unroll
            for (int jj = 0; jj < NSEG - 1; ++jj) if (jj < seg) off += tot[jj][lw];
            float run = off;
            #pragma unroll
            for (int k = 0; k < SEGLEN; ++k) { run += v[k]; ii[(h0 + k) * IW + col] = run; }
        }
        __syncthreads();
    }
    // ---- W cumsum ----
    {
        int row = lw + 1, w0 = seg * SEGLEN + 1;
        if (act) {
            float s = 0.0f;
            #pragma unroll
            for (int k = 0; k < SEGLEN; ++k) { v[k] = ii[row * IW + w0 + k]; s += v[k]; }
            tot[seg][lw] = s;
        }
        __syncthreads();
        if (act) {
            float off = 0.0f;
            #pragma unroll
            for (int jj = 0; jj < NSEG - 1; ++jj) if (jj < seg) off += tot[jj][lw];
            float run = off;
            #pragma unroll
            for (int k = 0; k < SEGLEN; ++k) { run += v[k]; ii[row * IW + w0 + k] = run; }
        }
        __syncthreads();
    }

    // ---- hot loop: all loads coalesced, 4 LDS reads, 1 mul, 1 store ----
    int j0 = base[b], j1 = base[b + 1];
    const uint2* tb = tab2 + (size_t)rem * R;
    for (int j = j0 + tid; j < j1; j += 512) {
        uint2 t = tb[j];
        int r = jlist[j];
        int hs =  t.x        & 255;
        int he = (t.x >> 8)  & 255;
        int ws = (t.x >> 16) & 255;
        int we =  t.x >> 24;
        float s = ((ii[he * IW + we] - ii[hs * IW + we])
                 -  ii[he * IW + ws]) + ii[hs * IW + ws];
        dst[(size_t)c * R + r] = s * __uint_as_float(t.y);
    }
}

// ---------- fallback: correctness-only direct path (ws too small) -----------
__global__ __launch_bounds__(256) void psroi_fallback_kernel(
    const float* __restrict__ feat, const float* __restrict__ rois,
    int R, float* __restrict__ out)
{
    __shared__ float ii[IW * IW];
    int bid = blockIdx.x;
    int b = bid / CC, c = bid % CC;
    int rem = c % 49, gh = rem / 7, gw = rem % 7;

    const float* plane = feat + ((size_t)b * CC + c) * PLANE;
    for (int i = threadIdx.x; i < PLANE; i += 256) {
        int h = i / WW, w = i % WW;
        ii[(h + 1) * IW + (w + 1)] = plane[i];
    }
    for (int i = threadIdx.x; i < IW; i += 256) { ii[i] = 0.0f; ii[i * IW] = 0.0f; }
    __syncthreads();
    if (threadIdx.x < WW) {
        int w = threadIdx.x + 1; float s = 0.0f;
        for (int h = 1; h <= HH; ++h) { s += ii[h * IW + w]; ii[h * IW + w] = s; }
    }
    __syncthreads();
    if (threadIdx.x < HH) {
        int h = threadIdx.x + 1; float* row = &ii[h * IW]; float s = 0.0f;
        for (int w = 1; w <= WW; ++w) { s += row[w]; row[w] = s; }
    }
    __syncthreads();
    for (int r = threadIdx.x; r < R; r += 256) {
        const float* roi = rois + (size_t)r * 5;
        if ((int)roi[0] != b) continue;
        float x1 = rintf(roi[1]) * 0.0625f;
        float y1 = rintf(roi[2]) * 0.0625f;
        float x2 = (rintf(roi[3]) + 1.0f) * 0.0625f;
        float y2 = (rintf(roi[4]) + 1.0f) * 0.0625f;
        float bw = fmaxf(x2 - x1, 0.1f) * recip7();
        float bh = fmaxf(y2 - y1, 0.1f) * recip7();
        asm volatile("" : "+v"(bw), "+v"(bh));
        int hs = (int)fminf(fmaxf(floorf(mul_add_nofma((float)gh,     bh, y1)), 0.0f), 80.0f);
        int he = (int)fminf(fmaxf(ceilf (mul_add_nofma((float)(gh+1), bh, y1)), 0.0f), 80.0f);
        int ws = (int)fminf(fmaxf(floorf(mul_add_nofma((float)gw,     bw, x1)), 0.0f), 80.0f);
        int we = (int)fminf(fmaxf(ceilf (mul_add_nofma((float)(gw+1), bw, x1)), 0.0f), 80.0f);
        float s = ii[he * IW + we] - ii[hs * IW + we] - ii[he * IW + ws] + ii[hs * IW + ws];
        int area = (he - hs) * (we - ws);
        out[(size_t)r * CC + c] = (area > 0) ? (s / (float)area) : 0.0f;
    }
}

// ---------- transpose: ws_T[1029][R] -> out[R][1029] ------------------------
__global__ __launch_bounds__(256) void transpose_kernel(
    const float* __restrict__ in, float* __restrict__ out, int R, int C)
{
    __shared__ float t[64][65];
    int r0 = blockIdx.x * 64;
    int c0 = blockIdx.y * 64;
    int tx = threadIdx.x, ty = threadIdx.y;

    #pragma unroll
    for (int k0 = 0; k0 < 64; k0 += 4) {
        int k = k0 + ty;
        int cc = c0 + k, rr = r0 + tx;
        if (cc < C && rr < R) t[k][tx] = in[(size_t)cc * R + rr];
    }
    __syncthreads();
    #pragma unroll
    for (int k0 = 0; k0 < 64; k0 += 4) {
        int k = k0 + ty;
        int rr = r0 + k, cc = c0 + tx;
        if (rr < R && cc < C) out[(size_t)rr * C + cc] = t[tx][k];
    }
}

extern "C" void kernel_launch(void* const* d_in, const int* in_sizes, int n_in,
                              void* d_out, int out_size, void* d_ws, size_t ws_size,
                              hipStream_t stream)
{
    const float* feat = (const float*)d_in[0];
    const float* rois = (const float*)d_in[1];
    float* out        = (float*)d_out;

    int R = in_sizes[1] / 5;
    int N = in_sizes[0] / (CC * PLANE);

    size_t off_wsT  = 0;
    size_t off_tab  = (off_wsT + (size_t)CC * R * sizeof(float) + 15) & ~(size_t)15;
    size_t off_jl   = (off_tab + (size_t)49 * R * sizeof(uint2) + 15) & ~(size_t)15;
    size_t off_base = off_jl + (size_t)R * sizeof(int);
    size_t need     = off_base + (size_t)(N + 1) * sizeof(int);

    if (ws_size >= need && N <= 8 && R <= 65536) {
        char* ws = (char*)d_ws;
        float* ws_T = (float*)(ws + off_wsT);
        uint2* tab2 = (uint2*)(ws + off_tab);
        int*   jl   = (int*)(ws + off_jl);
        int*   base = (int*)(ws + off_base);

        compact_kernel<<<1, 512, 0, stream>>>(rois, R, N, jl, base);
        edge_kernel<<<(49 * R + 255) / 256, 256, 0, stream>>>(rois, jl, base, N, R, tab2);
        psroi_plane_kernel<<<N * CC, 512, 0, stream>>>(feat, R, tab2, jl, base, ws_T);
        dim3 blk(64, 4), grd((R + 63) / 64, (CC + 63) / 64);
        transpose_kernel<<<grd, blk, 0, stream>>>(ws_T, out, R, CC);
    } else {
        psroi_fallback_kernel<<<N * CC, 256, 0, stream>>>(feat, rois, R, out);
    }
}

// Round 10
// 54.807 us; speedup vs baseline: 1.1418x; 1.1418x over previous
//
#include <hip/hip_runtime.h>

#define P   7
#define GS  7
#define D   21
#define HH  80
#define WW  80
#define CC  (D * GS * GS)        // 1029
#define PLANE (HH * WW)          // 6400 floats
#define IW  81                   // integral-image stride (odd: conflict-free cumsums)
#define NSEG 5
#define SEGLEN 16

// fl32(1/7) = 0x3E124925 — the golden divides via reciprocal multiply.
__device__ __forceinline__ float recip7() {
    union { unsigned u; float f; } c; c.u = 0x3E124925u; return c.f;
}

// a*b + c with a HARD barrier between mul and add: no fma contraction ever.
__device__ __forceinline__ float mul_add_nofma(float a, float b, float c) {
    float t = a * b;
    asm volatile("" : "+v"(t));
    return t + c;
}

// ---------- prep: edge tables + permutation jlist/base, one block -----------
__global__ __launch_bounds__(1024) void prep_kernel(
    const float* __restrict__ rois, int R, int N,
    unsigned short* __restrict__ hshe,
    unsigned short* __restrict__ wswe,
    int* __restrict__ jlist, int* __restrict__ base)
{
    __shared__ unsigned char bsh[2048];
    __shared__ int cntS[8];
    __shared__ int baseS[9];
    int tid = threadIdx.x;

    for (int r = tid; r < R; r += 1024) {
        const float* roi = rois + (size_t)r * 5;
        bsh[r] = (unsigned char)(int)roi[0];

        float x1 = rintf(roi[1]) * 0.0625f;
        float y1 = rintf(roi[2]) * 0.0625f;
        float x2 = (rintf(roi[3]) + 1.0f) * 0.0625f;
        float y2 = (rintf(roi[4]) + 1.0f) * 0.0625f;
        float bin_w = fmaxf(x2 - x1, 0.1f) * recip7();
        float bin_h = fmaxf(y2 - y1, 0.1f) * recip7();
        asm volatile("" : "+v"(bin_w), "+v"(bin_h));

        #pragma unroll
        for (int g = 0; g < 7; ++g) {
            float hs_f = floorf(mul_add_nofma((float)g,       bin_h, y1));
            float he_f = ceilf (mul_add_nofma((float)(g + 1), bin_h, y1));
            float ws_f = floorf(mul_add_nofma((float)g,       bin_w, x1));
            float we_f = ceilf (mul_add_nofma((float)(g + 1), bin_w, x1));
            int hs = (int)fminf(fmaxf(hs_f, 0.0f), 80.0f);
            int he = (int)fminf(fmaxf(he_f, 0.0f), 80.0f);
            int ws = (int)fminf(fmaxf(ws_f, 0.0f), 80.0f);
            int we = (int)fminf(fmaxf(we_f, 0.0f), 80.0f);
            hshe[r * 7 + g] = (unsigned short)(hs | (he << 8));
            wswe[r * 7 + g] = (unsigned short)(ws | (we << 8));
        }
    }
    __syncthreads();

    int wave = tid >> 6, lane = tid & 63;
    if (wave < N) {
        int b = wave, cnt = 0;
        for (int r0 = 0; r0 < R; r0 += 64) {
            int r = r0 + lane;
            bool m = (r < R) && (bsh[r] == (unsigned char)b);
            cnt += __popcll(__ballot(m));
        }
        if (lane == 0) cntS[b] = cnt;
    }
    __syncthreads();
    if (tid == 0) {
        int acc = 0;
        for (int b = 0; b < N; ++b) { baseS[b] = acc; acc += cntS[b]; }
        baseS[N] = acc;
    }
    __syncthreads();
    if (wave < N) {
        int b = wave, off = baseS[b];
        for (int r0 = 0; r0 < R; r0 += 64) {
            int r = r0 + lane;
            bool m = (r < R) && (bsh[r] == (unsigned char)b);
            unsigned long long mask = __ballot(m);
            int pos = off + __popcll(mask & ((1ull << lane) - 1ull));
            if (m) jlist[pos] = r;
            off += __popcll(mask);
        }
    }
    if (tid <= N) base[tid] = baseS[tid];
}

// ---------- plane kernel: low-VGPR LDS integral image + O(1) hot loop -------
__global__ __launch_bounds__(512, 8) void psroi_plane_kernel(
    const float* __restrict__ feat, int R,
    const unsigned short* __restrict__ hshe,
    const unsigned short* __restrict__ wswe,
    const int* __restrict__ jlist, const int* __restrict__ base,
    float* __restrict__ dst)          // ws_T[c][j], j = compacted index
{
    __shared__ float ii[IW * IW];     // 26.2 KB, zero border at row 0 / col 0
    __shared__ float tot[NSEG][HH];   // 1.6 KB

    int tid = threadIdx.x;
    int bid = blockIdx.x;
    int b   = bid / CC;
    int c   = bid % CC;
    int rem = c % (GS * GS);          // gh*7+gw
    int gh  = rem / GS;
    int gw  = rem % GS;

    // ---- stage plane into ii[1..80][1..80], float4 global loads ----
    const float4* src4 = (const float4*)(feat + ((size_t)b * CC + c) * PLANE);
    for (int i = tid; i < PLANE / 4; i += 512) {
        float4 v = src4[i];
        int h = i / 20;
        int w = (i % 20) * 4;
        float* p = &ii[(h + 1) * IW + (w + 1)];
        p[0] = v.x; p[1] = v.y; p[2] = v.z; p[3] = v.w;
    }
    if (tid < IW) { ii[tid] = 0.0f; ii[tid * IW] = 0.0f; }
    __syncthreads();

    bool act = tid < NSEG * WW;
    int seg = tid / WW;                // 0..4
    int lw  = tid % WW;                // 0..79

    // ---- H cumsum (axis=2 first, as golden): sum pass + apply pass ----
    {
        int col = lw + 1, h0 = seg * SEGLEN + 1;
        if (act) {
            float s = 0.0f;
            #pragma unroll 4
            for (int k = 0; k < SEGLEN; ++k) s += ii[(h0 + k) * IW + col];
            tot[seg][lw] = s;
        }
        __syncthreads();
        if (act) {
            float run = 0.0f;
            #pragma unroll
            for (int jj = 0; jj < NSEG - 1; ++jj) if (jj < seg) run += tot[jj][lw];
            #pragma unroll 4
            for (int k = 0; k < SEGLEN; ++k) {
                run += ii[(h0 + k) * IW + col];
                ii[(h0 + k) * IW + col] = run;
            }
        }
        __syncthreads();
    }
    // ---- W cumsum ----
    {
        int row = lw + 1, w0 = seg * SEGLEN + 1;
        if (act) {
            float s = 0.0f;
            #pragma unroll 4
            for (int k = 0; k < SEGLEN; ++k) s += ii[row * IW + w0 + k];
            tot[seg][lw] = s;
        }
        __syncthreads();
        if (act) {
            float run = 0.0f;
            #pragma unroll
            for (int jj = 0; jj < NSEG - 1; ++jj) if (jj < seg) run += tot[jj][lw];
            #pragma unroll 4
            for (int k = 0; k < SEGLEN; ++k) {
                run += ii[row * IW + w0 + k];
                ii[row * IW + w0 + k] = run;
            }
        }
        __syncthreads();
    }

    // ---- hot loop: coalesced jlist read, cached u16 tables, coalesced store ----
    int j0 = base[b], j1 = base[b + 1];
    for (int j = j0 + tid; j < j1; j += 512) {
        int r  = jlist[j];
        int hh = hshe[r * 7 + gh];
        int ww = wswe[r * 7 + gw];
        int hs = hh & 255, he = hh >> 8;
        int ws = ww & 255, we = ww >> 8;
        float s = ((ii[he * IW + we] - ii[hs * IW + we])
                 -  ii[he * IW + ws]) + ii[hs * IW + ws];
        int area = (he - hs) * (we - ws);
        dst[(size_t)c * R + j] = (area > 0) ? (s / (float)area) : 0.0f;
    }
}

// ---------- transpose: ws_T[1029][R](j-indexed) -> out[R][1029] -------------
__global__ __launch_bounds__(256) void transpose_kernel(
    const float* __restrict__ in, const int* __restrict__ jlist,
    float* __restrict__ out, int R, int C)
{
    __shared__ float t[64][65];
    __shared__ int rows[64];
    int j0 = blockIdx.x * 64;
    int c0 = blockIdx.y * 64;
    int tx = threadIdx.x, ty = threadIdx.y;
    int tid = ty * 64 + tx;

    if (tid < 64 && j0 + tid < R) rows[tid] = jlist[j0 + tid];

    #pragma unroll
    for (int k0 = 0; k0 < 64; k0 += 4) {
        int k = k0 + ty;
        int cc = c0 + k, jj = j0 + tx;
        if (cc < C && jj < R) t[k][tx] = in[(size_t)cc * R + jj];
    }
    __syncthreads();
    #pragma unroll
    for (int k0 = 0; k0 < 64; k0 += 4) {
        int k = k0 + ty;
        int cc = c0 + tx;
        if (j0 + k < R && cc < C) out[(size_t)rows[k] * C + cc] = t[tx][k];
    }
}

// ---------- fallback: correctness-only direct path (ws too small) -----------
__global__ __launch_bounds__(256) void psroi_fallback_kernel(
    const float* __restrict__ feat, const float* __restrict__ rois,
    int R, float* __restrict__ out)
{
    __shared__ float ii[IW * IW];
    int bid = blockIdx.x;
    int b = bid / CC, c = bid % CC;
    int rem = c % 49, gh = rem / 7, gw = rem % 7;

    const float* plane = feat + ((size_t)b * CC + c) * PLANE;
    for (int i = threadIdx.x; i < PLANE; i += 256) {
        int h = i / WW, w = i % WW;
        ii[(h + 1) * IW + (w + 1)] = plane[i];
    }
    for (int i = threadIdx.x; i < IW; i += 256) { ii[i] = 0.0f; ii[i * IW] = 0.0f; }
    __syncthreads();
    if (threadIdx.x < WW) {
        int w = threadIdx.x + 1; float s = 0.0f;
        for (int h = 1; h <= HH; ++h) { s += ii[h * IW + w]; ii[h * IW + w] = s; }
    }
    __syncthreads();
    if (threadIdx.x < HH) {
        int h = threadIdx.x + 1; float* row = &ii[h * IW]; float s = 0.0f;
        for (int w = 1; w <= WW; ++w) { s += row[w]; row[w] = s; }
    }
    __syncthreads();
    for (int r = threadIdx.x; r < R; r += 256) {
        const float* roi = rois + (size_t)r * 5;
        if ((int)roi[0] != b) continue;
        float x1 = rintf(roi[1]) * 0.0625f;
        float y1 = rintf(roi[2]) * 0.0625f;
        float x2 = (rintf(roi[3]) + 1.0f) * 0.0625f;
        float y2 = (rintf(roi[4]) + 1.0f) * 0.0625f;
        float bw = fmaxf(x2 - x1, 0.1f) * recip7();
        float bh = fmaxf(y2 - y1, 0.1f) * recip7();
        asm volatile("" : "+v"(bw), "+v"(bh));
        int hs = (int)fminf(fmaxf(floorf(mul_add_nofma((float)gh,     bh, y1)), 0.0f), 80.0f);
        int he = (int)fminf(fmaxf(ceilf (mul_add_nofma((float)(gh+1), bh, y1)), 0.0f), 80.0f);
        int ws = (int)fminf(fmaxf(floorf(mul_add_nofma((float)gw,     bw, x1)), 0.0f), 80.0f);
        int we = (int)fminf(fmaxf(ceilf (mul_add_nofma((float)(gw+1), bw, x1)), 0.0f), 80.0f);
        float s = ii[he * IW + we] - ii[hs * IW + we] - ii[he * IW + ws] + ii[hs * IW + ws];
        int area = (he - hs) * (we - ws);
        out[(size_t)r * CC + c] = (area > 0) ? (s / (float)area) : 0.0f;
    }
}

extern "C" void kernel_launch(void* const* d_in, const int* in_sizes, int n_in,
                              void* d_out, int out_size, void* d_ws, size_t ws_size,
                              hipStream_t stream)
{
    const float* feat = (const float*)d_in[0];
    const float* rois = (const float*)d_in[1];
    float* out        = (float*)d_out;

    int R = in_sizes[1] / 5;
    int N = in_sizes[0] / (CC * PLANE);

    size_t off_wsT  = 0;
    size_t off_hshe = (off_wsT + (size_t)CC * R * sizeof(float) + 15) & ~(size_t)15;
    size_t off_wswe = off_hshe + (size_t)R * 7 * sizeof(unsigned short);
    size_t off_jl   = (off_wswe + (size_t)R * 7 * sizeof(unsigned short) + 15) & ~(size_t)15;
    size_t off_base = off_jl + (size_t)R * sizeof(int);
    size_t need     = off_base + (size_t)(N + 1) * sizeof(int);

    if (ws_size >= need && N <= 8 && R <= 2048) {
        char* ws = (char*)d_ws;
        float*          ws_T = (float*)(ws + off_wsT);
        unsigned short* hshe = (unsigned short*)(ws + off_hshe);
        unsigned short* wswe = (unsigned short*)(ws + off_wswe);
        int*            jl   = (int*)(ws + off_jl);
        int*            base = (int*)(ws + off_base);

        prep_kernel<<<1, 1024, 0, stream>>>(rois, R, N, hshe, wswe, jl, base);
        psroi_plane_kernel<<<N * CC, 512, 0, stream>>>(feat, R, hshe, wswe, jl, base, ws_T);
        dim3 blk(64, 4), grd((R + 63) / 64, (CC + 63) / 64);
        transpose_kernel<<<grd, blk, 0, stream>>>(ws_T, jl, out, R, CC);
    } else {
        psroi_fallback_kernel<<<N * CC, 256, 0, stream>>>(feat, rois, R, out);
    }
}

// Round 11
// 46.127 us; speedup vs baseline: 1.3566x; 1.1882x over previous
//
#include <hip/hip_runtime.h>

#define P   7
#define GS  7
#define D   21
#define HH  80
#define WW  80
#define CC  (D * GS * GS)        // 1029
#define PLANE (HH * WW)          // 6400 floats
#define IW  81                   // integral-image stride (odd: conflict-free cumsums)
#define NSEG 5
#define SEGLEN 16

// fl32(1/7) = 0x3E124925 — the golden divides via reciprocal multiply.
__device__ __forceinline__ float recip7() {
    union { unsigned u; float f; } c; c.u = 0x3E124925u; return c.f;
}

// a*b + c with a HARD barrier between mul and add: no fma contraction ever.
__device__ __forceinline__ float mul_add_nofma(float a, float b, float c) {
    float t = a * b;
    asm volatile("" : "+v"(t));
    return t + c;
}

// ---------- prep: edges + parallel 2-level ballot compaction, one block -----
__global__ __launch_bounds__(1024) void prep_kernel(
    const float* __restrict__ rois, int R, int N,
    unsigned short* __restrict__ hshe,
    unsigned short* __restrict__ wswe,
    int* __restrict__ jlist, int* __restrict__ base)
{
    __shared__ unsigned char bsh[2048];
    __shared__ int wcnt[16][8];
    __shared__ int wbase[16][8];
    __shared__ int baseS[9];
    int tid = threadIdx.x, wave = tid >> 6, lane = tid & 63;

    // ---- edge tables (exact golden arithmetic) ----
    for (int r = tid; r < R; r += 1024) {
        const float* roi = rois + (size_t)r * 5;
        bsh[r] = (unsigned char)(int)roi[0];

        float x1 = rintf(roi[1]) * 0.0625f;
        float y1 = rintf(roi[2]) * 0.0625f;
        float x2 = (rintf(roi[3]) + 1.0f) * 0.0625f;
        float y2 = (rintf(roi[4]) + 1.0f) * 0.0625f;
        float bin_w = fmaxf(x2 - x1, 0.1f) * recip7();
        float bin_h = fmaxf(y2 - y1, 0.1f) * recip7();
        asm volatile("" : "+v"(bin_w), "+v"(bin_h));

        #pragma unroll
        for (int g = 0; g < 7; ++g) {
            float hs_f = floorf(mul_add_nofma((float)g,       bin_h, y1));
            float he_f = ceilf (mul_add_nofma((float)(g + 1), bin_h, y1));
            float ws_f = floorf(mul_add_nofma((float)g,       bin_w, x1));
            float we_f = ceilf (mul_add_nofma((float)(g + 1), bin_w, x1));
            int hs = (int)fminf(fmaxf(hs_f, 0.0f), 80.0f);
            int he = (int)fminf(fmaxf(he_f, 0.0f), 80.0f);
            int ws = (int)fminf(fmaxf(ws_f, 0.0f), 80.0f);
            int we = (int)fminf(fmaxf(we_f, 0.0f), 80.0f);
            hshe[r * 7 + g] = (unsigned short)(hs | (he << 8));
            wswe[r * 7 + g] = (unsigned short)(ws | (we << 8));
        }
    }
    __syncthreads();

    // ---- level 1: per-wave per-batch counts over its r-chunk ----
    int chunk = (R + 15) / 16;
    int rbeg = wave * chunk;
    int rend = min(rbeg + chunk, R);
    int cnt[8];
    #pragma unroll
    for (int b = 0; b < 8; ++b) cnt[b] = 0;
    for (int rr = rbeg + lane; rr < rend; rr += 64) {
        int bv = bsh[rr];
        #pragma unroll
        for (int b = 0; b < 8; ++b) {
            if (b < N) cnt[b] += __popcll(__ballot(bv == b));
        }
    }
    // NOTE: lanes with rr>=rend exit loop at different trip counts only at the
    // chunk tail; ballot inside requires all lanes — make trips uniform:
    // (chunk is multiple of 64 when R==2048; general case handled below)
    if (lane == 0) {
        #pragma unroll
        for (int b = 0; b < 8; ++b) wcnt[wave][b] = cnt[b];
    }
    __syncthreads();

    // ---- level 2: prefix over waves, then over batches ----
    if (tid < 8) {
        int b = tid, acc = 0;
        for (int w = 0; w < 16; ++w) { wbase[w][b] = acc; acc += wcnt[w][b]; }
        baseS[b] = acc;                    // total count of batch b (temp)
    }
    __syncthreads();
    if (tid == 0) {
        int acc = 0;
        for (int b = 0; b < N; ++b) { int t = baseS[b]; baseS[b] = acc; acc += t; }
        baseS[N] = acc;
    }
    __syncthreads();

    // ---- write pass: stable order ----
    {
        int off[8];
        #pragma unroll
        for (int b = 0; b < 8; ++b) off[b] = (b < N) ? (baseS[b] + wbase[wave][b]) : 0;
        for (int rr = rbeg + lane; rr < rend; rr += 64) {
            int bv = bsh[rr];
            #pragma unroll
            for (int b = 0; b < 8; ++b) {
                if (b < N) {
                    unsigned long long mask = __ballot(bv == b);
                    if (bv == b) {
                        int pos = off[b] + __popcll(mask & ((1ull << lane) - 1ull));
                        jlist[pos] = rr;
                    }
                    off[b] += __popcll(mask);
                }
            }
        }
    }
    if (tid <= N) base[tid] = baseS[tid];
}

// ---------- plane kernel: reg-carry II + early hot-loop prefetch ------------
__global__ __launch_bounds__(512) void psroi_plane_kernel(
    const float* __restrict__ feat, int R,
    const unsigned short* __restrict__ hshe,
    const unsigned short* __restrict__ wswe,
    const int* __restrict__ jlist, const int* __restrict__ base,
    float* __restrict__ dst)          // ws_T[c][j], j = compacted index
{
    __shared__ float ii[IW * IW];     // 26.2 KB
    __shared__ float tot[NSEG][HH];   // 1.6 KB

    int tid = threadIdx.x;
    int bid = blockIdx.x;
    int b   = bid / CC;
    int c   = bid % CC;
    int rem = c % (GS * GS);
    int gh  = rem / GS;
    int gw  = rem % GS;

    // ---- stage plane into ii[1..80][1..80], float4 global loads ----
    const float4* src4 = (const float4*)(feat + ((size_t)b * CC + c) * PLANE);
    for (int i = tid; i < PLANE / 4; i += 512) {
        float4 v = src4[i];
        int h = i / 20;
        int w = (i % 20) * 4;
        float* p = &ii[(h + 1) * IW + (w + 1)];
        p[0] = v.x; p[1] = v.y; p[2] = v.z; p[3] = v.w;
    }

    // ---- early prefetch of hot-loop gathers (overlap with cumsums) ----
    int j0 = base[b], j1 = base[b + 1];
    int jA = j0 + tid, jB = jA + 512, jC = jA + 1024, jD = jA + 1536;
    int rA = (jA < j1) ? jlist[jA] : 0;
    int rB = (jB < j1) ? jlist[jB] : 0;
    int rC = (jC < j1) ? jlist[jC] : 0;
    int rD = (jD < j1) ? jlist[jD] : 0;
    unsigned hA = (jA < j1) ? hshe[rA * 7 + gh] : 0;
    unsigned wA = (jA < j1) ? wswe[rA * 7 + gw] : 0;
    unsigned hB = (jB < j1) ? hshe[rB * 7 + gh] : 0;
    unsigned wB = (jB < j1) ? wswe[rB * 7 + gw] : 0;
    unsigned hC = (jC < j1) ? hshe[rC * 7 + gh] : 0;
    unsigned wC = (jC < j1) ? wswe[rC * 7 + gw] : 0;
    unsigned hD = (jD < j1) ? hshe[rD * 7 + gh] : 0;
    unsigned wD = (jD < j1) ? wswe[rD * 7 + gw] : 0;

    if (tid < IW) { ii[tid] = 0.0f; ii[tid * IW] = 0.0f; }
    __syncthreads();

    bool act = tid < NSEG * WW;
    int seg = tid / WW;                // 0..4
    int lw  = tid % WW;                // 0..79
    float v[SEGLEN];

    // ---- H cumsum (axis=2 first, as golden): register-carry 2-level ----
    {
        int col = lw + 1, h0 = seg * SEGLEN + 1;
        if (act) {
            float s = 0.0f;
            #pragma unroll
            for (int k = 0; k < SEGLEN; ++k) { v[k] = ii[(h0 + k) * IW + col]; s += v[k]; }
            tot[seg][lw] = s;
        }
        __syncthreads();
        if (act) {
            float off = 0.0f;
            #pragma unroll
            for (int jj = 0; jj < NSEG - 1; ++jj) if (jj < seg) off += tot[jj][lw];
            float run = off;
            #pragma unroll
            for (int k = 0; k < SEGLEN; ++k) { run += v[k]; ii[(h0 + k) * IW + col] = run; }
        }
        __syncthreads();
    }
    // ---- W cumsum ----
    {
        int row = lw + 1, w0 = seg * SEGLEN + 1;
        if (act) {
            float s = 0.0f;
            #pragma unroll
            for (int k = 0; k < SEGLEN; ++k) { v[k] = ii[row * IW + w0 + k]; s += v[k]; }
            tot[seg][lw] = s;
        }
        __syncthreads();
        if (act) {
            float off = 0.0f;
            #pragma unroll
            for (int jj = 0; jj < NSEG - 1; ++jj) if (jj < seg) off += tot[jj][lw];
            float run = off;
            #pragma unroll
            for (int k = 0; k < SEGLEN; ++k) { run += v[k]; ii[row * IW + w0 + k] = run; }
        }
        __syncthreads();
    }

    // ---- hot loop: only LDS reads + math + coalesced store remain ----
    #define EMIT(jX, hX, wX)                                                  \
    if (jX < j1) {                                                            \
        int hs = hX & 255, he = (int)(hX >> 8);                               \
        int ws = wX & 255, we = (int)(wX >> 8);                               \
        float s = ((ii[he * IW + we] - ii[hs * IW + we])                      \
                 -  ii[he * IW + ws]) + ii[hs * IW + ws];                     \
        int area = (he - hs) * (we - ws);                                     \
        dst[(size_t)c * R + jX] = (area > 0) ? (s / (float)area) : 0.0f;      \
    }
    EMIT(jA, hA, wA)
    EMIT(jB, hB, wB)
    EMIT(jC, hC, wC)
    EMIT(jD, hD, wD)
    #undef EMIT
}

// ---------- transpose: ws_T[1029][R](j-indexed) -> out[R][1029] -------------
__global__ __launch_bounds__(256) void transpose_kernel(
    const float* __restrict__ in, const int* __restrict__ jlist,
    float* __restrict__ out, int R, int C)
{
    __shared__ float t[64][65];
    __shared__ int rows[64];
    int j0 = blockIdx.x * 64;
    int c0 = blockIdx.y * 64;
    int tx = threadIdx.x, ty = threadIdx.y;
    int tid = ty * 64 + tx;

    if (tid < 64 && j0 + tid < R) rows[tid] = jlist[j0 + tid];

    #pragma unroll
    for (int k0 = 0; k0 < 64; k0 += 4) {
        int k = k0 + ty;
        int cc = c0 + k, jj = j0 + tx;
        if (cc < C && jj < R) t[k][tx] = in[(size_t)cc * R + jj];
    }
    __syncthreads();
    #pragma unroll
    for (int k0 = 0; k0 < 64; k0 += 4) {
        int k = k0 + ty;
        int cc = c0 + tx;
        if (j0 + k < R && cc < C) out[(size_t)rows[k] * C + cc] = t[tx][k];
    }
}

// ---------- fallback: correctness-only direct path (ws too small) -----------
__global__ __launch_bounds__(256) void psroi_fallback_kernel(
    const float* __restrict__ feat, const float* __restrict__ rois,
    int R, float* __restrict__ out)
{
    __shared__ float ii[IW * IW];
    int bid = blockIdx.x;
    int b = bid / CC, c = bid % CC;
    int rem = c % 49, gh = rem / 7, gw = rem % 7;

    const float* plane = feat + ((size_t)b * CC + c) * PLANE;
    for (int i = threadIdx.x; i < PLANE; i += 256) {
        int h = i / WW, w = i % WW;
        ii[(h + 1) * IW + (w + 1)] = plane[i];
    }
    for (int i = threadIdx.x; i < IW; i += 256) { ii[i] = 0.0f; ii[i * IW] = 0.0f; }
    __syncthreads();
    if (threadIdx.x < WW) {
        int w = threadIdx.x + 1; float s = 0.0f;
        for (int h = 1; h <= HH; ++h) { s += ii[h * IW + w]; ii[h * IW + w] = s; }
    }
    __syncthreads();
    if (threadIdx.x < HH) {
        int h = threadIdx.x + 1; float* row = &ii[h * IW]; float s = 0.0f;
        for (int w = 1; w <= WW; ++w) { s += row[w]; row[w] = s; }
    }
    __syncthreads();
    for (int r = threadIdx.x; r < R; r += 256) {
        const float* roi = rois + (size_t)r * 5;
        if ((int)roi[0] != b) continue;
        float x1 = rintf(roi[1]) * 0.0625f;
        float y1 = rintf(roi[2]) * 0.0625f;
        float x2 = (rintf(roi[3]) + 1.0f) * 0.0625f;
        float y2 = (rintf(roi[4]) + 1.0f) * 0.0625f;
        float bw = fmaxf(x2 - x1, 0.1f) * recip7();
        float bh = fmaxf(y2 - y1, 0.1f) * recip7();
        asm volatile("" : "+v"(bw), "+v"(bh));
        int hs = (int)fminf(fmaxf(floorf(mul_add_nofma((float)gh,     bh, y1)), 0.0f), 80.0f);
        int he = (int)fminf(fmaxf(ceilf (mul_add_nofma((float)(gh+1), bh, y1)), 0.0f), 80.0f);
        int ws = (int)fminf(fmaxf(floorf(mul_add_nofma((float)gw,     bw, x1)), 0.0f), 80.0f);
        int we = (int)fminf(fmaxf(ceilf (mul_add_nofma((float)(gw+1), bw, x1)), 0.0f), 80.0f);
        float s = ii[he * IW + we] - ii[hs * IW + we] - ii[he * IW + ws] + ii[hs * IW + ws];
        int area = (he - hs) * (we - ws);
        out[(size_t)r * CC + c] = (area > 0) ? (s / (float)area) : 0.0f;
    }
}

extern "C" void kernel_launch(void* const* d_in, const int* in_sizes, int n_in,
                              void* d_out, int out_size, void* d_ws, size_t ws_size,
                              hipStream_t stream)
{
    const float* feat = (const float*)d_in[0];
    const float* rois = (const float*)d_in[1];
    float* out        = (float*)d_out;

    int R = in_sizes[1] / 5;
    int N = in_sizes[0] / (CC * PLANE);

    size_t off_wsT  = 0;
    size_t off_hshe = (off_wsT + (size_t)CC * R * sizeof(float) + 15) & ~(size_t)15;
    size_t off_wswe = off_hshe + (size_t)R * 7 * sizeof(unsigned short);
    size_t off_jl   = (off_wswe + (size_t)R * 7 * sizeof(unsigned short) + 15) & ~(size_t)15;
    size_t off_base = off_jl + (size_t)R * sizeof(int);
    size_t need     = off_base + (size_t)(N + 1) * sizeof(int);

    // parallel-prep requires R divisible by 1024-chunking assumptions only in
    // the uniform-ballot sense: chunk multiple of 64. R=2048 -> chunk=128 ✓.
    bool chunk_ok = (((R + 15) / 16) % 64) == 0;

    if (ws_size >= need && N <= 8 && R <= 2048 && chunk_ok) {
        char* ws = (char*)d_ws;
        float*          ws_T = (float*)(ws + off_wsT);
        unsigned short* hshe = (unsigned short*)(ws + off_hshe);
        unsigned short* wswe = (unsigned short*)(ws + off_wswe);
        int*            jl   = (int*)(ws + off_jl);
        int*            base = (int*)(ws + off_base);

        prep_kernel<<<1, 1024, 0, stream>>>(rois, R, N, hshe, wswe, jl, base);
        psroi_plane_kernel<<<N * CC, 512, 0, stream>>>(feat, R, hshe, wswe, jl, base, ws_T);
        dim3 blk(64, 4), grd((R + 63) / 64, (CC + 63) / 64);
        transpose_kernel<<<grd, blk, 0, stream>>>(ws_T, jl, out, R, CC);
    } else {
        psroi_fallback_kernel<<<N * CC, 256, 0, stream>>>(feat, rois, R, out);
    }
}

// Round 12
// 45.579 us; speedup vs baseline: 1.3729x; 1.0120x over previous
//
#include <hip/hip_runtime.h>

#define P   7
#define GS  7
#define D   21
#define HH  80
#define WW  80
#define CC  (D * GS * GS)        // 1029
#define PLANE (HH * WW)          // 6400 floats
#define IW  84                   // row stride: 16B-aligned rows, bank-stride 20 mod 32
#define NSEG 5
#define SEGLEN 16

// fl32(1/7) = 0x3E124925 — the golden divides via reciprocal multiply.
__device__ __forceinline__ float recip7() {
    union { unsigned u; float f; } c; c.u = 0x3E124925u; return c.f;
}

// a*b + c with a HARD barrier between mul and add: no fma contraction ever.
__device__ __forceinline__ float mul_add_nofma(float a, float b, float c) {
    float t = a * b;
    asm volatile("" : "+v"(t));
    return t + c;
}

// ---------- prep: edges + parallel 2-level ballot compaction, one block -----
__global__ __launch_bounds__(1024) void prep_kernel(
    const float* __restrict__ rois, int R, int N,
    unsigned short* __restrict__ hshe,
    unsigned short* __restrict__ wswe,
    int* __restrict__ jlist, int* __restrict__ base)
{
    __shared__ unsigned char bsh[2048];
    __shared__ int wcnt[16][8];
    __shared__ int wbase[16][8];
    __shared__ int baseS[9];
    int tid = threadIdx.x, wave = tid >> 6, lane = tid & 63;

    for (int r = tid; r < R; r += 1024) {
        const float* roi = rois + (size_t)r * 5;
        bsh[r] = (unsigned char)(int)roi[0];

        float x1 = rintf(roi[1]) * 0.0625f;
        float y1 = rintf(roi[2]) * 0.0625f;
        float x2 = (rintf(roi[3]) + 1.0f) * 0.0625f;
        float y2 = (rintf(roi[4]) + 1.0f) * 0.0625f;
        float bin_w = fmaxf(x2 - x1, 0.1f) * recip7();
        float bin_h = fmaxf(y2 - y1, 0.1f) * recip7();
        asm volatile("" : "+v"(bin_w), "+v"(bin_h));

        #pragma unroll
        for (int g = 0; g < 7; ++g) {
            float hs_f = floorf(mul_add_nofma((float)g,       bin_h, y1));
            float he_f = ceilf (mul_add_nofma((float)(g + 1), bin_h, y1));
            float ws_f = floorf(mul_add_nofma((float)g,       bin_w, x1));
            float we_f = ceilf (mul_add_nofma((float)(g + 1), bin_w, x1));
            int hs = (int)fminf(fmaxf(hs_f, 0.0f), 80.0f);
            int he = (int)fminf(fmaxf(he_f, 0.0f), 80.0f);
            int ws = (int)fminf(fmaxf(ws_f, 0.0f), 80.0f);
            int we = (int)fminf(fmaxf(we_f, 0.0f), 80.0f);
            hshe[r * 7 + g] = (unsigned short)(hs | (he << 8));
            wswe[r * 7 + g] = (unsigned short)(ws | (we << 8));
        }
    }
    __syncthreads();

    int chunk = (R + 15) / 16;
    int rbeg = wave * chunk;
    int rend = min(rbeg + chunk, R);
    int cnt[8];
    #pragma unroll
    for (int b = 0; b < 8; ++b) cnt[b] = 0;
    for (int rr = rbeg + lane; rr < rend; rr += 64) {
        int bv = bsh[rr];
        #pragma unroll
        for (int b = 0; b < 8; ++b) {
            if (b < N) cnt[b] += __popcll(__ballot(bv == b));
        }
    }
    if (lane == 0) {
        #pragma unroll
        for (int b = 0; b < 8; ++b) wcnt[wave][b] = cnt[b];
    }
    __syncthreads();

    if (tid < 8) {
        int b = tid, acc = 0;
        for (int w = 0; w < 16; ++w) { wbase[w][b] = acc; acc += wcnt[w][b]; }
        baseS[b] = acc;
    }
    __syncthreads();
    if (tid == 0) {
        int acc = 0;
        for (int b = 0; b < N; ++b) { int t = baseS[b]; baseS[b] = acc; acc += t; }
        baseS[N] = acc;
    }
    __syncthreads();

    {
        int off[8];
        #pragma unroll
        for (int b = 0; b < 8; ++b) off[b] = (b < N) ? (baseS[b] + wbase[wave][b]) : 0;
        for (int rr = rbeg + lane; rr < rend; rr += 64) {
            int bv = bsh[rr];
            #pragma unroll
            for (int b = 0; b < 8; ++b) {
                if (b < N) {
                    unsigned long long mask = __ballot(bv == b);
                    if (bv == b) {
                        int pos = off[b] + __popcll(mask & ((1ull << lane) - 1ull));
                        jlist[pos] = rr;
                    }
                    off[b] += __popcll(mask);
                }
            }
        }
    }
    if (tid <= N) base[tid] = baseS[tid];
}

// ---------- plane kernel: b128 LDS integral image + guarded O(1) hot loop ---
__global__ __launch_bounds__(512) void psroi_plane_kernel(
    const float* __restrict__ feat, int R,
    const unsigned short* __restrict__ hshe,
    const unsigned short* __restrict__ wswe,
    const int* __restrict__ jlist, const int* __restrict__ base,
    float* __restrict__ dst)          // ws_T[c][j], j = compacted index
{
    __shared__ float ii[HH * IW];     // [80][84], no border; cols 80..83 junk
    __shared__ float tot[NSEG][HH];   // 1.6 KB

    int tid = threadIdx.x;
    int bid = blockIdx.x;
    int b   = bid / CC;
    int c   = bid % CC;
    int rem = c % (GS * GS);
    int gh  = rem / GS;
    int gw  = rem % GS;

    // ---- stage plane: aligned ds_write_b128 (row*84 + 4k is 16B-aligned) ----
    const float4* src4 = (const float4*)(feat + ((size_t)b * CC + c) * PLANE);
    for (int i = tid; i < PLANE / 4; i += 512) {
        float4 v = src4[i];
        int h = i / 20;
        int w = (i % 20) * 4;
        *(float4*)(&ii[h * IW + w]) = v;
    }

    // ---- early prefetch of hot-loop gathers (overlap with cumsums) ----
    int j0 = base[b], j1 = base[b + 1];
    int jA = j0 + tid, jB = jA + 512, jC = jA + 1024, jD = jA + 1536;
    int rA = (jA < j1) ? jlist[jA] : 0;
    int rB = (jB < j1) ? jlist[jB] : 0;
    int rC = (jC < j1) ? jlist[jC] : 0;
    int rD = (jD < j1) ? jlist[jD] : 0;
    unsigned hA = (jA < j1) ? hshe[rA * 7 + gh] : 0;
    unsigned wA = (jA < j1) ? wswe[rA * 7 + gw] : 0;
    unsigned hB = (jB < j1) ? hshe[rB * 7 + gh] : 0;
    unsigned wB = (jB < j1) ? wswe[rB * 7 + gw] : 0;
    unsigned hC = (jC < j1) ? hshe[rC * 7 + gh] : 0;
    unsigned wC = (jC < j1) ? wswe[rC * 7 + gw] : 0;
    unsigned hD = (jD < j1) ? hshe[rD * 7 + gh] : 0;
    unsigned wD = (jD < j1) ? wswe[rD * 7 + gw] : 0;

    __syncthreads();

    bool act = tid < NSEG * WW;
    int seg = tid / WW;                // 0..4
    int lw  = tid % WW;                // 0..79

    // ---- H cumsum (axis=2 first, as golden): b32, register carry ----
    {
        float v[SEGLEN];
        int col = lw, h0 = seg * SEGLEN;
        if (act) {
            float s = 0.0f;
            #pragma unroll
            for (int k = 0; k < SEGLEN; ++k) { v[k] = ii[(h0 + k) * IW + col]; s += v[k]; }
            tot[seg][lw] = s;
        }
        __syncthreads();
        if (act) {
            float off = 0.0f;
            #pragma unroll
            for (int jj = 0; jj < NSEG - 1; ++jj) if (jj < seg) off += tot[jj][lw];
            float run = off;
            #pragma unroll
            for (int k = 0; k < SEGLEN; ++k) { run += v[k]; ii[(h0 + k) * IW + col] = run; }
        }
        __syncthreads();
    }
    // ---- W cumsum: b128 float4 segments, register carry ----
    {
        float4 q0, q1, q2, q3;
        int row = lw, w0 = seg * SEGLEN;
        float4* rp = (float4*)&ii[row * IW + w0];
        if (act) {
            q0 = rp[0]; q1 = rp[1]; q2 = rp[2]; q3 = rp[3];
            float s = (((((q0.x + q0.y) + (q0.z + q0.w))
                       + ((q1.x + q1.y) + (q1.z + q1.w)))
                      + (((q2.x + q2.y) + (q2.z + q2.w))
                       + ((q3.x + q3.y) + (q3.z + q3.w)))));
            // NOTE: tot is only used as a plain sum offset; pairwise assoc is fine
            // because the APPLY pass below recomputes the in-order running sum —
            // but offsets must equal the in-order segment total exactly.
            // Use strict in-order sum instead:
            s = q0.x; s += q0.y; s += q0.z; s += q0.w;
            s += q1.x; s += q1.y; s += q1.z; s += q1.w;
            s += q2.x; s += q2.y; s += q2.z; s += q2.w;
            s += q3.x; s += q3.y; s += q3.z; s += q3.w;
            tot[seg][row] = s;
        }
        __syncthreads();
        if (act) {
            float off = 0.0f;
            #pragma unroll
            for (int jj = 0; jj < NSEG - 1; ++jj) if (jj < seg) off += tot[jj][row];
            float run = off;
            run += q0.x; q0.x = run; run += q0.y; q0.y = run;
            run += q0.z; q0.z = run; run += q0.w; q0.w = run;
            run += q1.x; q1.x = run; run += q1.y; q1.y = run;
            run += q1.z; q1.z = run; run += q1.w; q1.w = run;
            run += q2.x; q2.x = run; run += q2.y; q2.y = run;
            run += q2.z; q2.z = run; run += q2.w; q2.w = run;
            run += q3.x; q3.x = run; run += q3.y; q3.y = run;
            run += q3.z; q3.z = run; run += q3.w; q3.w = run;
            rp[0] = q0; rp[1] = q1; rp[2] = q2; rp[3] = q3;
        }
        __syncthreads();
    }

    // ---- hot loop: guarded II lookups (II(h,w)=ii[h-1][w-1], 0 if h==0||w==0) ----
    #define IIV(hq, wq) ( ((hq) > 0 && (wq) > 0)                              \
        ? ii[((hq) - 1) * IW + ((wq) - 1)] : 0.0f )
    #define EMIT(jX, hX, wX)                                                  \
    if (jX < j1) {                                                            \
        int hs = hX & 255, he = (int)(hX >> 8);                               \
        int ws = wX & 255, we = (int)(wX >> 8);                               \
        float s = ((IIV(he, we) - IIV(hs, we))                                \
                 -  IIV(he, ws)) + IIV(hs, ws);                               \
        int area = (he - hs) * (we - ws);                                     \
        dst[(size_t)c * R + jX] = (area > 0) ? (s / (float)area) : 0.0f;      \
    }
    EMIT(jA, hA, wA)
    EMIT(jB, hB, wB)
    EMIT(jC, hC, wC)
    EMIT(jD, hD, wD)
    #undef EMIT
    #undef IIV
}

// ---------- transpose: ws_T[1029][R](j-indexed) -> out[R][1029] -------------
__global__ __launch_bounds__(256) void transpose_kernel(
    const float* __restrict__ in, const int* __restrict__ jlist,
    float* __restrict__ out, int R, int C)
{
    __shared__ float t[64][65];
    __shared__ int rows[64];
    int j0 = blockIdx.x * 64;
    int c0 = blockIdx.y * 64;
    int tx = threadIdx.x, ty = threadIdx.y;
    int tid = ty * 64 + tx;

    if (tid < 64 && j0 + tid < R) rows[tid] = jlist[j0 + tid];

    #pragma unroll
    for (int k0 = 0; k0 < 64; k0 += 4) {
        int k = k0 + ty;
        int cc = c0 + k, jj = j0 + tx;
        if (cc < C && jj < R) t[k][tx] = in[(size_t)cc * R + jj];
    }
    __syncthreads();
    #pragma unroll
    for (int k0 = 0; k0 < 64; k0 += 4) {
        int k = k0 + ty;
        int cc = c0 + tx;
        if (j0 + k < R && cc < C) out[(size_t)rows[k] * C + cc] = t[tx][k];
    }
}

// ---------- fallback: correctness-only direct path (ws too small) -----------
__global__ __launch_bounds__(256) void psroi_fallback_kernel(
    const float* __restrict__ feat, const float* __restrict__ rois,
    int R, float* __restrict__ out)
{
    __shared__ float ii[81 * 81];
    int bid = blockIdx.x;
    int b = bid / CC, c = bid % CC;
    int rem = c % 49, gh = rem / 7, gw = rem % 7;

    const float* plane = feat + ((size_t)b * CC + c) * PLANE;
    for (int i = threadIdx.x; i < PLANE; i += 256) {
        int h = i / WW, w = i % WW;
        ii[(h + 1) * 81 + (w + 1)] = plane[i];
    }
    for (int i = threadIdx.x; i < 81; i += 256) { ii[i] = 0.0f; ii[i * 81] = 0.0f; }
    __syncthreads();
    if (threadIdx.x < WW) {
        int w = threadIdx.x + 1; float s = 0.0f;
        for (int h = 1; h <= HH; ++h) { s += ii[h * 81 + w]; ii[h * 81 + w] = s; }
    }
    __syncthreads();
    if (threadIdx.x < HH) {
        int h = threadIdx.x + 1; float* row = &ii[h * 81]; float s = 0.0f;
        for (int w = 1; w <= WW; ++w) { s += row[w]; row[w] = s; }
    }
    __syncthreads();
    for (int r = threadIdx.x; r < R; r += 256) {
        const float* roi = rois + (size_t)r * 5;
        if ((int)roi[0] != b) continue;
        float x1 = rintf(roi[1]) * 0.0625f;
        float y1 = rintf(roi[2]) * 0.0625f;
        float x2 = (rintf(roi[3]) + 1.0f) * 0.0625f;
        float y2 = (rintf(roi[4]) + 1.0f) * 0.0625f;
        float bw = fmaxf(x2 - x1, 0.1f) * recip7();
        float bh = fmaxf(y2 - y1, 0.1f) * recip7();
        asm volatile("" : "+v"(bw), "+v"(bh));
        int hs = (int)fminf(fmaxf(floorf(mul_add_nofma((float)gh,     bh, y1)), 0.0f), 80.0f);
        int he = (int)fminf(fmaxf(ceilf (mul_add_nofma((float)(gh+1), bh, y1)), 0.0f), 80.0f);
        int ws = (int)fminf(fmaxf(floorf(mul_add_nofma((float)gw,     bw, x1)), 0.0f), 80.0f);
        int we = (int)fminf(fmaxf(ceilf (mul_add_nofma((float)(gw+1), bw, x1)), 0.0f), 80.0f);
        float s = ii[he * 81 + we] - ii[hs * 81 + we] - ii[he * 81 + ws] + ii[hs * 81 + ws];
        int area = (he - hs) * (we - ws);
        out[(size_t)r * CC + c] = (area > 0) ? (s / (float)area) : 0.0f;
    }
}

extern "C" void kernel_launch(void* const* d_in, const int* in_sizes, int n_in,
                              void* d_out, int out_size, void* d_ws, size_t ws_size,
                              hipStream_t stream)
{
    const float* feat = (const float*)d_in[0];
    const float* rois = (const float*)d_in[1];
    float* out        = (float*)d_out;

    int R = in_sizes[1] / 5;
    int N = in_sizes[0] / (CC * PLANE);

    size_t off_wsT  = 0;
    size_t off_hshe = (off_wsT + (size_t)CC * R * sizeof(float) + 15) & ~(size_t)15;
    size_t off_wswe = off_hshe + (size_t)R * 7 * sizeof(unsigned short);
    size_t off_jl   = (off_wswe + (size_t)R * 7 * sizeof(unsigned short) + 15) & ~(size_t)15;
    size_t off_base = off_jl + (size_t)R * sizeof(int);
    size_t need     = off_base + (size_t)(N + 1) * sizeof(int);

    bool chunk_ok = (((R + 15) / 16) % 64) == 0;

    if (ws_size >= need && N <= 8 && R <= 2048 && chunk_ok) {
        char* ws = (char*)d_ws;
        float*          ws_T = (float*)(ws + off_wsT);
        unsigned short* hshe = (unsigned short*)(ws + off_hshe);
        unsigned short* wswe = (unsigned short*)(ws + off_wswe);
        int*            jl   = (int*)(ws + off_jl);
        int*            base = (int*)(ws + off_base);

        prep_kernel<<<1, 1024, 0, stream>>>(rois, R, N, hshe, wswe, jl, base);
        psroi_plane_kernel<<<N * CC, 512, 0, stream>>>(feat, R, hshe, wswe, jl, base, ws_T);
        dim3 blk(64, 4), grd((R + 63) / 64, (CC + 63) / 64);
        transpose_kernel<<<grd, blk, 0, stream>>>(ws_T, jl, out, R, CC);
    } else {
        psroi_fallback_kernel<<<N * CC, 256, 0, stream>>>(feat, rois, R, out);
    }
}